// Round 1
// baseline (322.704 us; speedup 1.0000x reference)
//
#include <hip/hip_runtime.h>
#include <hip/hip_bf16.h>

// MemoryEfficientAttention: O = softmax(Q K^T / sqrt(D)) V
// [B,H,S,D] = [2,16,2048,128], fp32 in/out, bf16 MFMA compute.
//
// Round 0: flash-attention structure, correctness-first.
//  - 4 waves/block, each wave owns 16 q-rows (64-row Q tile per block)
//  - KVBLK=32 staged fp32->bf16 into LDS; V stored transposed for PV B-frags
//  - mfma_f32_16x16x32_bf16 for both QK^T and PV; fp32 accum + online softmax
//  - P reshaped C-layout -> A-layout via per-wave LDS bounce (no barrier needed:
//    same-wave DS ops are ordered)

typedef short short8 __attribute__((ext_vector_type(8)));
typedef float f32x4 __attribute__((ext_vector_type(4)));

#define MFMA16(a, b, c) __builtin_amdgcn_mfma_f32_16x16x32_bf16((a), (b), (c), 0, 0, 0)

constexpr int Dh    = 128;
constexpr int KVBLK = 32;
constexpr int QW    = 16;            // q rows per wave
constexpr int WAVES = 4;
constexpr int QBLK  = QW * WAVES;    // 64 q rows per block
constexpr int KPAD  = 136;           // K row pad: stride 272B -> 2-way bank alias (free)
constexpr int VPAD  = 40;            // vT row pad: stride 80B -> 2-way (free)
constexpr int PPAD  = 40;

__device__ __forceinline__ short f2bf(float f) {
    union { float f; unsigned u; } x; x.f = f;
    unsigned r = x.u + 0x7fffu + ((x.u >> 16) & 1u);   // RNE
    return (short)(r >> 16);
}

__global__ __launch_bounds__(256, 2)
void mea_fwd(const float* __restrict__ Qg, const float* __restrict__ Kg,
             const float* __restrict__ Vg, float* __restrict__ Og,
             int S, int nqt) {
    __shared__ __align__(16) short k_lds[KVBLK][KPAD];
    __shared__ __align__(16) short vT_lds[Dh][VPAD];
    __shared__ __align__(16) short p_lds[WAVES][16][PPAD];

    const int qt   = blockIdx.x % nqt;
    const int bh   = blockIdx.x / nqt;
    const int tid  = threadIdx.x;
    const int w    = tid >> 6;
    const int lane = tid & 63;
    const int lr   = lane & 15;   // lane % 16
    const int lg   = lane >> 4;   // lane / 16 (0..3)

    const size_t base  = (size_t)bh * S * Dh;
    const int    qrow0 = qt * QBLK + w * QW;
    const float  scale = 0.08838834764831845f;   // 1/sqrt(128)

    // ---- Q fragments: lane holds Q[qrow0 + lr][kc*32 + lg*8 .. +7] (A-layout) ----
    short8 qf[4];
    {
        const float* qp = Qg + base + (size_t)(qrow0 + lr) * Dh;
        #pragma unroll
        for (int kc = 0; kc < 4; ++kc) {
            const float4 f0 = *(const float4*)(qp + kc * 32 + lg * 8);
            const float4 f1 = *(const float4*)(qp + kc * 32 + lg * 8 + 4);
            short8 a;
            a[0] = f2bf(f0.x); a[1] = f2bf(f0.y); a[2] = f2bf(f0.z); a[3] = f2bf(f0.w);
            a[4] = f2bf(f1.x); a[5] = f2bf(f1.y); a[6] = f2bf(f1.z); a[7] = f2bf(f1.w);
            qf[kc] = a;
        }
    }

    f32x4 oacc[8];
    #pragma unroll
    for (int dt = 0; dt < 8; ++dt) oacc[dt] = (f32x4){0.f, 0.f, 0.f, 0.f};
    float mrun[4] = {-1e30f, -1e30f, -1e30f, -1e30f};
    float lrun[4] = {0.f, 0.f, 0.f, 0.f};

    // staging decomposition: 256 threads cover 32 rows x 128 cols, 16 cols/thread
    const int sr = tid >> 3;          // kv row 0..31
    const int sc = (tid & 7) * 16;    // d col 0,16,...,112

    for (int kv0 = 0; kv0 < S; kv0 += KVBLK) {
        // ---- stage K (row-major bf16) and V^T (d-major bf16) ----
        {
            const float* kp = Kg + base + (size_t)(kv0 + sr) * Dh + sc;
            const float* vp = Vg + base + (size_t)(kv0 + sr) * Dh + sc;
            short8 pk0, pk1;
            {
                float4 f0 = ((const float4*)kp)[0];
                float4 f1 = ((const float4*)kp)[1];
                float4 f2 = ((const float4*)kp)[2];
                float4 f3 = ((const float4*)kp)[3];
                pk0[0] = f2bf(f0.x); pk0[1] = f2bf(f0.y); pk0[2] = f2bf(f0.z); pk0[3] = f2bf(f0.w);
                pk0[4] = f2bf(f1.x); pk0[5] = f2bf(f1.y); pk0[6] = f2bf(f1.z); pk0[7] = f2bf(f1.w);
                pk1[0] = f2bf(f2.x); pk1[1] = f2bf(f2.y); pk1[2] = f2bf(f2.z); pk1[3] = f2bf(f2.w);
                pk1[4] = f2bf(f3.x); pk1[5] = f2bf(f3.y); pk1[6] = f2bf(f3.z); pk1[7] = f2bf(f3.w);
            }
            *(short8*)&k_lds[sr][sc]     = pk0;
            *(short8*)&k_lds[sr][sc + 8] = pk1;
            #pragma unroll
            for (int i = 0; i < 4; ++i) {
                float4 f = ((const float4*)vp)[i];
                vT_lds[sc + 4 * i + 0][sr] = f2bf(f.x);
                vT_lds[sc + 4 * i + 1][sr] = f2bf(f.y);
                vT_lds[sc + 4 * i + 2][sr] = f2bf(f.z);
                vT_lds[sc + 4 * i + 3][sr] = f2bf(f.w);
            }
        }
        __syncthreads();

        // ---- S = Q K^T  (two 16x16 kv column-tiles, K-dim = 128 via 4 MFMA each) ----
        f32x4 s0 = (f32x4){0.f, 0.f, 0.f, 0.f};
        f32x4 s1 = (f32x4){0.f, 0.f, 0.f, 0.f};
        #pragma unroll
        for (int kc = 0; kc < 4; ++kc) {
            short8 b0 = *(const short8*)&k_lds[lr][kc * 32 + lg * 8];
            short8 b1 = *(const short8*)&k_lds[16 + lr][kc * 32 + lg * 8];
            s0 = MFMA16(qf[kc], b0, s0);
            s1 = MFMA16(qf[kc], b1, s1);
        }

        // ---- online softmax: 4 rows per lane (C-layout row = lg*4+r) ----
        float resc[4];
        #pragma unroll
        for (int r = 0; r < 4; ++r) {
            float mx = fmaxf(s0[r], s1[r]);
            #pragma unroll
            for (int m = 1; m < 16; m <<= 1) mx = fmaxf(mx, __shfl_xor(mx, m));
            float mnew = fmaxf(mrun[r], mx * scale);
            float rc   = __expf(mrun[r] - mnew);
            mrun[r] = mnew;
            float p0 = __expf(s0[r] * scale - mnew);
            float p1 = __expf(s1[r] * scale - mnew);
            float rs = p0 + p1;
            #pragma unroll
            for (int m = 1; m < 16; m <<= 1) rs += __shfl_xor(rs, m);
            lrun[r] = lrun[r] * rc + rs;
            resc[r] = rc;
            // P -> per-wave LDS bounce (bf16), C-layout write
            p_lds[w][lg * 4 + r][lr]      = f2bf(p0);
            p_lds[w][lg * 4 + r][16 + lr] = f2bf(p1);
        }

        // rescale O accumulators
        #pragma unroll
        for (int dt = 0; dt < 8; ++dt) {
            f32x4 o = oacc[dt];
            o[0] *= resc[0]; o[1] *= resc[1]; o[2] *= resc[2]; o[3] *= resc[3];
            oacc[dt] = o;
        }

        // ---- O += P V : A-frag of P from LDS, B-frag from vT ----
        short8 ap = *(const short8*)&p_lds[w][lr][lg * 8];
        #pragma unroll
        for (int dt = 0; dt < 8; ++dt) {
            short8 bv = *(const short8*)&vT_lds[dt * 16 + lr][lg * 8];
            oacc[dt] = MFMA16(ap, bv, oacc[dt]);
        }
        __syncthreads();
    }

    // ---- epilogue: divide by l, store fp32 ----
    float inv[4];
    #pragma unroll
    for (int r = 0; r < 4; ++r) inv[r] = 1.0f / lrun[r];
    float* op = Og + base;
    #pragma unroll
    for (int dt = 0; dt < 8; ++dt)
        #pragma unroll
        for (int r = 0; r < 4; ++r)
            op[(size_t)(qrow0 + lg * 4 + r) * Dh + dt * 16 + lr] = oacc[dt][r] * inv[r];
}

extern "C" void kernel_launch(void* const* d_in, const int* in_sizes, int n_in,
                              void* d_out, int out_size, void* d_ws, size_t ws_size,
                              hipStream_t stream) {
    const float* q = (const float*)d_in[0];
    const float* k = (const float*)d_in[1];
    const float* v = (const float*)d_in[2];
    float* o = (float*)d_out;

    const int S  = 2048;
    const int BH = in_sizes[0] / (S * Dh);   // B*H = 32
    const int nqt = S / QBLK;                // 32

    dim3 grid(BH * nqt), block(WAVES * 64);
    hipLaunchKernelGGL(mea_fwd, grid, block, 0, stream, q, k, v, o, S, nqt);
}

// Round 2
// 174.192 us; speedup vs baseline: 1.8526x; 1.8526x over previous
//
#include <hip/hip_runtime.h>
#include <hip/hip_bf16.h>

// MemoryEfficientAttention round 2:
//  - pre-pass converts K -> bf16 (16B blocks XOR-swizzled by row&15) and
//    V -> bf16 transposed KV-tile-contiguous [bh][seg][d][64] (blocks XOR'd by d&7)
//  - main kernel stages K/V tiles with global_load_lds width-16 (no staging VALU,
//    no LDS write conflicts); all ds_read_b128 <= 2-way aliased (free)
//  - KVBLK=64 (2x MFMA per barrier), defer-max rescale skip (T13, THR=8)

typedef short short8 __attribute__((ext_vector_type(8)));
typedef float f32x4 __attribute__((ext_vector_type(4)));

#define MFMA16(a, b, c) __builtin_amdgcn_mfma_f32_16x16x32_bf16((a), (b), (c), 0, 0, 0)

constexpr int Dh = 128;
constexpr int S_ = 2048;

__device__ __forceinline__ short f2bf(float f) {
    union { float f; unsigned u; } x; x.f = f;
    unsigned r = x.u + 0x7fffu + ((x.u >> 16) & 1u);   // RNE
    return (short)(r >> 16);
}

__device__ __forceinline__ void gload16(const void* g, void* l) {
    __builtin_amdgcn_global_load_lds(
        (const __attribute__((address_space(1))) unsigned int*)g,
        (__attribute__((address_space(3))) unsigned int*)l, 16, 0, 0);
}

// ---------------- pre-pass: K fp32 -> bf16, blocks swizzled ----------------
// Kz[row][blk] = K[row][blk ^ (s&15)]  (16 x 16B blocks per 128-elem row)
__global__ __launch_bounds__(256) void prep_k(const float* __restrict__ K,
                                              short* __restrict__ Kz) {
    int idx = blockIdx.x * 256 + threadIdx.x;     // one 16B out block
    int b   = idx & 15;
    int s   = (idx >> 4) & (S_ - 1);
    int sb  = b ^ (s & 15);
    const float* src = K + (size_t)(idx >> 4) * Dh + sb * 8;
    float4 f0 = ((const float4*)src)[0];
    float4 f1 = ((const float4*)src)[1];
    short8 o;
    o[0] = f2bf(f0.x); o[1] = f2bf(f0.y); o[2] = f2bf(f0.z); o[3] = f2bf(f0.w);
    o[4] = f2bf(f1.x); o[5] = f2bf(f1.y); o[6] = f2bf(f1.z); o[7] = f2bf(f1.w);
    *(short8*)(Kz + (size_t)idx * 8) = o;
}

// ---------------- pre-pass: V fp32 -> bf16 transposed tiles ----------------
// Vt[bh][seg][d][64]: row d holds V[seg*64 .. +63][d]; 16B block j stores
// s-block (j ^ (d&7)).
__global__ __launch_bounds__(256) void prep_v(const float* __restrict__ V,
                                              short* __restrict__ Vt) {
    __shared__ short tr[64][72];
    int bid = blockIdx.x;
    int dg = bid & 1, seg = (bid >> 1) & 31, bh = bid >> 6;
    int t = threadIdx.x;
    int s = t >> 2, d0 = (t & 3) * 16;
    const float* src = V + (size_t)(bh * S_ + seg * 64 + s) * Dh + dg * 64 + d0;
    #pragma unroll
    for (int i = 0; i < 16; i += 4) {
        float4 f = *(const float4*)(src + i);
        tr[d0 + i + 0][s] = f2bf(f.x); tr[d0 + i + 1][s] = f2bf(f.y);
        tr[d0 + i + 2][s] = f2bf(f.z); tr[d0 + i + 3][s] = f2bf(f.w);
    }
    __syncthreads();
    int d = t >> 2, j0 = (t & 3) * 2;
    size_t ob = ((size_t)(bh * 32 + seg) * 128 + dg * 64 + d) * 64;
    #pragma unroll
    for (int jj = 0; jj < 2; ++jj) {
        int j = j0 + jj;
        int sj = (j ^ (d & 7)) * 8;
        short8 val = *(const short8*)&tr[d][sj];
        *(short8*)(Vt + ob + j * 8) = val;
    }
}

// ---------------- main flash kernel ----------------
constexpr int KVB   = 64;
constexpr int WAVES = 4;
constexpr int QBLK  = 64;
constexpr int PPAD  = 72;

__global__ __launch_bounds__(256, 2)
void mea_fwd2(const float* __restrict__ Qg, const short* __restrict__ Kz,
              const short* __restrict__ Vt, float* __restrict__ Og, int nqt) {
    __shared__ __align__(16) short k_lds[KVB * Dh];
    __shared__ __align__(16) short v_lds[Dh * KVB];
    __shared__ __align__(16) short p_lds[WAVES][16][PPAD];

    const int qt   = blockIdx.x % nqt;
    const int bh   = blockIdx.x / nqt;
    const int tid  = threadIdx.x;
    const int w    = tid >> 6;
    const int lane = tid & 63;
    const int lr   = lane & 15;
    const int lg   = lane >> 4;

    const size_t base  = (size_t)bh * S_ * Dh;
    const int    qrow0 = qt * QBLK + w * 16;
    const float  scale = 0.08838834764831845f;   // 1/sqrt(128)

    // Q fragments (A-layout): lane holds Q[qrow0+lr][kc*32 + lg*8 .. +7]
    short8 qf[4];
    {
        const float* qp = Qg + base + (size_t)(qrow0 + lr) * Dh;
        #pragma unroll
        for (int kc = 0; kc < 4; ++kc) {
            const float4 f0 = *(const float4*)(qp + kc * 32 + lg * 8);
            const float4 f1 = *(const float4*)(qp + kc * 32 + lg * 8 + 4);
            short8 a;
            a[0] = f2bf(f0.x); a[1] = f2bf(f0.y); a[2] = f2bf(f0.z); a[3] = f2bf(f0.w);
            a[4] = f2bf(f1.x); a[5] = f2bf(f1.y); a[6] = f2bf(f1.z); a[7] = f2bf(f1.w);
            qf[kc] = a;
        }
    }

    f32x4 oacc[8];
    #pragma unroll
    for (int dt = 0; dt < 8; ++dt) oacc[dt] = (f32x4){0.f, 0.f, 0.f, 0.f};
    float mrun[4] = {-1e30f, -1e30f, -1e30f, -1e30f};
    float lrun[4] = {0.f, 0.f, 0.f, 0.f};

    const short* ktile0 = Kz + (size_t)bh * S_ * Dh;
    const short* vtile0 = Vt + (size_t)bh * 32 * Dh * 64;

    for (int kv0 = 0; kv0 < S_; kv0 += KVB) {
        // ---- stage 16KB K-tile + 16KB V^T-tile, 1KB per wave-issue ----
        const short* kt = ktile0 + (size_t)kv0 * Dh;
        const short* vt = vtile0 + (size_t)(kv0 >> 6) * Dh * 64;
        #pragma unroll
        for (int i = 0; i < 4; ++i) {
            int o = (i * 4 + w) * 512;
            gload16(kt + o + lane * 8, &k_lds[o]);
        }
        #pragma unroll
        for (int i = 0; i < 4; ++i) {
            int o = (i * 4 + w) * 512;
            gload16(vt + o + lane * 8, &v_lds[o]);
        }
        __syncthreads();

        // ---- S = Q K^T : 4 col-tiles x K=128 (4 kc) = 16 MFMA ----
        f32x4 sac[4];
        #pragma unroll
        for (int ct = 0; ct < 4; ++ct) sac[ct] = (f32x4){0.f, 0.f, 0.f, 0.f};
        #pragma unroll
        for (int kc = 0; kc < 4; ++kc) {
            #pragma unroll
            for (int ct = 0; ct < 4; ++ct) {
                int row = ct * 16 + lr;
                int blk = (kc * 4 + lg) ^ lr;          // 4-bit XOR -> conflict-free
                short8 b = *(const short8*)&k_lds[row * Dh + blk * 8];
                sac[ct] = MFMA16(qf[kc], b, sac[ct]);
            }
        }

        // ---- online softmax, defer-max (THR=8) ----
        float mx[4];
        bool need = false;
        #pragma unroll
        for (int r = 0; r < 4; ++r) {
            float m0 = fmaxf(fmaxf(sac[0][r], sac[1][r]), fmaxf(sac[2][r], sac[3][r]));
            #pragma unroll
            for (int mm = 1; mm < 16; mm <<= 1) m0 = fmaxf(m0, __shfl_xor(m0, mm));
            mx[r] = m0 * scale;
            need |= (mx[r] > mrun[r] + 8.0f);
        }
        if (__any(need)) {
            #pragma unroll
            for (int r = 0; r < 4; ++r) {
                float mnew = fmaxf(mrun[r], mx[r]);
                float rc = __expf(mrun[r] - mnew);
                mrun[r] = mnew;
                lrun[r] *= rc;
                #pragma unroll
                for (int dt = 0; dt < 8; ++dt) oacc[dt][r] *= rc;
            }
        }
        #pragma unroll
        for (int r = 0; r < 4; ++r) {
            float rs = 0.f;
            #pragma unroll
            for (int ct = 0; ct < 4; ++ct) {
                float p = __expf(sac[ct][r] * scale - mrun[r]);
                rs += p;
                p_lds[w][lg * 4 + r][ct * 16 + lr] = f2bf(p);
            }
            #pragma unroll
            for (int mm = 1; mm < 16; mm <<= 1) rs += __shfl_xor(rs, mm);
            lrun[r] += rs;
        }

        // ---- O += P V : 8 d-tiles x K=64 (2 kc) = 16 MFMA ----
        short8 ap0 = *(const short8*)&p_lds[w][lr][lg * 8];
        short8 ap1 = *(const short8*)&p_lds[w][lr][32 + lg * 8];
        #pragma unroll
        for (int dt = 0; dt < 8; ++dt) {
            int row = dt * 16 + lr;
            short8 b0 = *(const short8*)&v_lds[row * KVB + ((lg) ^ (lr & 7)) * 8];
            short8 b1 = *(const short8*)&v_lds[row * KVB + ((4 + lg) ^ (lr & 7)) * 8];
            oacc[dt] = MFMA16(ap0, b0, oacc[dt]);
            oacc[dt] = MFMA16(ap1, b1, oacc[dt]);
        }
        __syncthreads();
    }

    float inv[4];
    #pragma unroll
    for (int r = 0; r < 4; ++r) inv[r] = 1.0f / lrun[r];
    float* op = Og + base;
    #pragma unroll
    for (int dt = 0; dt < 8; ++dt)
        #pragma unroll
        for (int r = 0; r < 4; ++r)
            op[(size_t)(qrow0 + lg * 4 + r) * Dh + dt * 16 + lr] = oacc[dt][r] * inv[r];
}

// ---------------- fallback (round-1 kernel, used only if ws too small) -----
constexpr int FKVB = 32;
constexpr int FKP  = 136;
constexpr int FVP  = 40;
constexpr int FPP  = 40;

__global__ __launch_bounds__(256, 2)
void mea_fwd_fb(const float* __restrict__ Qg, const float* __restrict__ Kg,
                const float* __restrict__ Vg, float* __restrict__ Og,
                int S, int nqt) {
    __shared__ __align__(16) short k_lds[FKVB][FKP];
    __shared__ __align__(16) short vT_lds[Dh][FVP];
    __shared__ __align__(16) short p_lds[4][16][FPP];

    const int qt = blockIdx.x % nqt;
    const int bh = blockIdx.x / nqt;
    const int tid = threadIdx.x;
    const int w = tid >> 6, lane = tid & 63;
    const int lr = lane & 15, lg = lane >> 4;
    const size_t base = (size_t)bh * S * Dh;
    const int qrow0 = qt * 64 + w * 16;
    const float scale = 0.08838834764831845f;

    short8 qf[4];
    {
        const float* qp = Qg + base + (size_t)(qrow0 + lr) * Dh;
        #pragma unroll
        for (int kc = 0; kc < 4; ++kc) {
            const float4 f0 = *(const float4*)(qp + kc * 32 + lg * 8);
            const float4 f1 = *(const float4*)(qp + kc * 32 + lg * 8 + 4);
            short8 a;
            a[0] = f2bf(f0.x); a[1] = f2bf(f0.y); a[2] = f2bf(f0.z); a[3] = f2bf(f0.w);
            a[4] = f2bf(f1.x); a[5] = f2bf(f1.y); a[6] = f2bf(f1.z); a[7] = f2bf(f1.w);
            qf[kc] = a;
        }
    }
    f32x4 oacc[8];
    #pragma unroll
    for (int dt = 0; dt < 8; ++dt) oacc[dt] = (f32x4){0.f, 0.f, 0.f, 0.f};
    float mrun[4] = {-1e30f, -1e30f, -1e30f, -1e30f};
    float lrun[4] = {0.f, 0.f, 0.f, 0.f};
    const int sr = tid >> 3, sc = (tid & 7) * 16;

    for (int kv0 = 0; kv0 < S; kv0 += FKVB) {
        {
            const float* kp = Kg + base + (size_t)(kv0 + sr) * Dh + sc;
            const float* vp = Vg + base + (size_t)(kv0 + sr) * Dh + sc;
            short8 pk0, pk1;
            float4 f0 = ((const float4*)kp)[0], f1 = ((const float4*)kp)[1];
            float4 f2 = ((const float4*)kp)[2], f3 = ((const float4*)kp)[3];
            pk0[0] = f2bf(f0.x); pk0[1] = f2bf(f0.y); pk0[2] = f2bf(f0.z); pk0[3] = f2bf(f0.w);
            pk0[4] = f2bf(f1.x); pk0[5] = f2bf(f1.y); pk0[6] = f2bf(f1.z); pk0[7] = f2bf(f1.w);
            pk1[0] = f2bf(f2.x); pk1[1] = f2bf(f2.y); pk1[2] = f2bf(f2.z); pk1[3] = f2bf(f2.w);
            pk1[4] = f2bf(f3.x); pk1[5] = f2bf(f3.y); pk1[6] = f2bf(f3.z); pk1[7] = f2bf(f3.w);
            *(short8*)&k_lds[sr][sc] = pk0;
            *(short8*)&k_lds[sr][sc + 8] = pk1;
            #pragma unroll
            for (int i = 0; i < 4; ++i) {
                float4 f = ((const float4*)vp)[i];
                vT_lds[sc + 4 * i + 0][sr] = f2bf(f.x);
                vT_lds[sc + 4 * i + 1][sr] = f2bf(f.y);
                vT_lds[sc + 4 * i + 2][sr] = f2bf(f.z);
                vT_lds[sc + 4 * i + 3][sr] = f2bf(f.w);
            }
        }
        __syncthreads();
        f32x4 s0 = (f32x4){0.f,0.f,0.f,0.f}, s1 = (f32x4){0.f,0.f,0.f,0.f};
        #pragma unroll
        for (int kc = 0; kc < 4; ++kc) {
            short8 b0 = *(const short8*)&k_lds[lr][kc * 32 + lg * 8];
            short8 b1 = *(const short8*)&k_lds[16 + lr][kc * 32 + lg * 8];
            s0 = MFMA16(qf[kc], b0, s0);
            s1 = MFMA16(qf[kc], b1, s1);
        }
        float resc[4];
        #pragma unroll
        for (int r = 0; r < 4; ++r) {
            float mxv = fmaxf(s0[r], s1[r]);
            #pragma unroll
            for (int m = 1; m < 16; m <<= 1) mxv = fmaxf(mxv, __shfl_xor(mxv, m));
            float mnew = fmaxf(mrun[r], mxv * scale);
            float rc = __expf(mrun[r] - mnew);
            mrun[r] = mnew;
            float p0 = __expf(s0[r] * scale - mnew);
            float p1 = __expf(s1[r] * scale - mnew);
            float rs = p0 + p1;
            #pragma unroll
            for (int m = 1; m < 16; m <<= 1) rs += __shfl_xor(rs, m);
            lrun[r] = lrun[r] * rc + rs;
            resc[r] = rc;
            p_lds[w][lg * 4 + r][lr] = f2bf(p0);
            p_lds[w][lg * 4 + r][16 + lr] = f2bf(p1);
        }
        #pragma unroll
        for (int dt = 0; dt < 8; ++dt) {
            f32x4 o = oacc[dt];
            o[0] *= resc[0]; o[1] *= resc[1]; o[2] *= resc[2]; o[3] *= resc[3];
            oacc[dt] = o;
        }
        short8 ap = *(const short8*)&p_lds[w][lr][lg * 8];
        #pragma unroll
        for (int dt = 0; dt < 8; ++dt) {
            short8 bv = *(const short8*)&vT_lds[dt * 16 + lr][lg * 8];
            oacc[dt] = MFMA16(ap, bv, oacc[dt]);
        }
        __syncthreads();
    }
    float inv[4];
    #pragma unroll
    for (int r = 0; r < 4; ++r) inv[r] = 1.0f / lrun[r];
    float* op = Og + base;
    #pragma unroll
    for (int dt = 0; dt < 8; ++dt)
        #pragma unroll
        for (int r = 0; r < 4; ++r)
            op[(size_t)(qrow0 + lg * 4 + r) * Dh + dt * 16 + lr] = oacc[dt][r] * inv[r];
}

extern "C" void kernel_launch(void* const* d_in, const int* in_sizes, int n_in,
                              void* d_out, int out_size, void* d_ws, size_t ws_size,
                              hipStream_t stream) {
    const float* q = (const float*)d_in[0];
    const float* k = (const float*)d_in[1];
    const float* v = (const float*)d_in[2];
    float* o = (float*)d_out;

    const int BH  = in_sizes[0] / (S_ * Dh);     // 32
    const int nqt = S_ / QBLK;                    // 32

    const size_t kz_bytes = (size_t)BH * S_ * Dh * sizeof(short);   // 16.78 MB
    const size_t need = 2 * kz_bytes;

    if (ws_size >= need) {
        short* Kz = (short*)d_ws;
        short* Vt = (short*)((char*)d_ws + kz_bytes);
        hipLaunchKernelGGL(prep_k, dim3(BH * S_ * 16 / 256), dim3(256), 0, stream, k, Kz);
        hipLaunchKernelGGL(prep_v, dim3(BH * (S_ / 64) * 2), dim3(256), 0, stream, v, Vt);
        hipLaunchKernelGGL(mea_fwd2, dim3(BH * nqt), dim3(256), 0, stream, q, Kz, Vt, o, nqt);
    } else {
        hipLaunchKernelGGL(mea_fwd_fb, dim3(BH * (S_ / 64)), dim3(256), 0, stream,
                           q, k, v, o, S_, S_ / 64);
    }
}

// Round 3
// 113.941 us; speedup vs baseline: 2.8322x; 1.5288x over previous
//
#include <hip/hip_runtime.h>
#include <hip/hip_bf16.h>

// MemoryEfficientAttention round 3:
//  - 8 waves/block, QBLK=128 -> 2 blocks/CU, 4 waves/SIMD (2x occupancy)
//  - double-buffered K/V LDS, stage-ahead with ONE barrier per tile (T3 2-phase)
//  - base-2 softmax (scale*log2e folded into Q), lane-local defer-max check,
//    per-lane deferred row-sum (no per-tile shuffles on common path)
//  - s_setprio(1) around MFMA clusters (T5)
//  - pre-pass: K -> bf16 XOR-swizzled; V -> bf16 transposed tiles (unchanged)

typedef short short8 __attribute__((ext_vector_type(8)));
typedef float f32x4 __attribute__((ext_vector_type(4)));

#define MFMA16(a, b, c) __builtin_amdgcn_mfma_f32_16x16x32_bf16((a), (b), (c), 0, 0, 0)

#if __has_builtin(__builtin_amdgcn_exp2f)
#define EXP2(x) __builtin_amdgcn_exp2f(x)
#else
#define EXP2(x) exp2f(x)
#endif

constexpr int Dh  = 128;
constexpr int S_  = 2048;
constexpr int KVB = 64;
constexpr int NT  = S_ / KVB;          // 32 kv tiles
constexpr int WAVES = 8;
constexpr int QBLK  = 128;             // 8 waves x 16 q-rows

__device__ __forceinline__ short f2bf(float f) {
    union { float f; unsigned u; } x; x.f = f;
    unsigned r = x.u + 0x7fffu + ((x.u >> 16) & 1u);   // RNE
    return (short)(r >> 16);
}

__device__ __forceinline__ void gload16(const void* g, void* l) {
    __builtin_amdgcn_global_load_lds(
        (const __attribute__((address_space(1))) unsigned int*)g,
        (__attribute__((address_space(3))) unsigned int*)l, 16, 0, 0);
}

// ---------------- pre-pass: K fp32 -> bf16, 16B blocks XOR'd by row&15 -----
__global__ __launch_bounds__(256) void prep_k(const float* __restrict__ K,
                                              short* __restrict__ Kz) {
    int idx = blockIdx.x * 256 + threadIdx.x;     // one 16B out block
    int b   = idx & 15;
    int s   = (idx >> 4) & (S_ - 1);
    int sb  = b ^ (s & 15);
    const float* src = K + (size_t)(idx >> 4) * Dh + sb * 8;
    float4 f0 = ((const float4*)src)[0];
    float4 f1 = ((const float4*)src)[1];
    short8 o;
    o[0] = f2bf(f0.x); o[1] = f2bf(f0.y); o[2] = f2bf(f0.z); o[3] = f2bf(f0.w);
    o[4] = f2bf(f1.x); o[5] = f2bf(f1.y); o[6] = f2bf(f1.z); o[7] = f2bf(f1.w);
    *(short8*)(Kz + (size_t)idx * 8) = o;
}

// ---------------- pre-pass: V fp32 -> bf16 transposed tiles ----------------
// Vt[bh][seg][d][64]: row d holds V[seg*64 .. +63][d]; 16B block j stores
// s-block (j ^ (d&7)).
__global__ __launch_bounds__(256) void prep_v(const float* __restrict__ V,
                                              short* __restrict__ Vt) {
    __shared__ short tr[64][72];
    int bid = blockIdx.x;
    int dg = bid & 1, seg = (bid >> 1) & 31, bh = bid >> 6;
    int t = threadIdx.x;
    int s = t >> 2, d0 = (t & 3) * 16;
    const float* src = V + (size_t)(bh * S_ + seg * 64 + s) * Dh + dg * 64 + d0;
    #pragma unroll
    for (int i = 0; i < 16; i += 4) {
        float4 f = *(const float4*)(src + i);
        tr[d0 + i + 0][s] = f2bf(f.x); tr[d0 + i + 1][s] = f2bf(f.y);
        tr[d0 + i + 2][s] = f2bf(f.z); tr[d0 + i + 3][s] = f2bf(f.w);
    }
    __syncthreads();
    int d = t >> 2, j0 = (t & 3) * 2;
    size_t ob = ((size_t)(bh * 32 + seg) * 128 + dg * 64 + d) * 64;
    #pragma unroll
    for (int jj = 0; jj < 2; ++jj) {
        int j = j0 + jj;
        int sj = (j ^ (d & 7)) * 8;
        short8 val = *(const short8*)&tr[d][sj];
        *(short8*)(Vt + ob + j * 8) = val;
    }
}

// ---------------- main flash kernel (8-wave, double-buffered) --------------
__global__ __launch_bounds__(512, 4)
void mea_fwd3(const float* __restrict__ Qg, const short* __restrict__ Kz,
              const short* __restrict__ Vt, float* __restrict__ Og, int nqt) {
    __shared__ __align__(16) short k0[KVB * Dh], k1[KVB * Dh];
    __shared__ __align__(16) short v0[Dh * KVB], v1[Dh * KVB];
    __shared__ __align__(16) short p_lds[WAVES][16][64];   // XOR-swizzled

    // bijective XCD swizzle (gridDim.x % 8 == 0): 4 bh per XCD -> KV fits L2
    const int bid  = blockIdx.x;
    const int swz  = (bid & 7) * ((int)gridDim.x >> 3) + (bid >> 3);
    const int qt   = swz % nqt;
    const int bh   = swz / nqt;
    const int tid  = threadIdx.x;
    const int w    = tid >> 6;
    const int lane = tid & 63;
    const int lr   = lane & 15;
    const int lg   = lane >> 4;

    const size_t base  = (size_t)bh * S_ * Dh;
    const int    qrow0 = qt * QBLK + w * 16;
    // softmax in base-2: fold scale * log2(e) into Q before bf16 conversion
    const float  QSC = 0.08838834764831845f * 1.4426950408889634f;

    // Q fragments (A-layout), pre-scaled
    short8 qf[4];
    {
        const float* qp = Qg + base + (size_t)(qrow0 + lr) * Dh;
        #pragma unroll
        for (int kc = 0; kc < 4; ++kc) {
            const float4 f0 = *(const float4*)(qp + kc * 32 + lg * 8);
            const float4 f1 = *(const float4*)(qp + kc * 32 + lg * 8 + 4);
            short8 a;
            a[0] = f2bf(f0.x * QSC); a[1] = f2bf(f0.y * QSC);
            a[2] = f2bf(f0.z * QSC); a[3] = f2bf(f0.w * QSC);
            a[4] = f2bf(f1.x * QSC); a[5] = f2bf(f1.y * QSC);
            a[6] = f2bf(f1.z * QSC); a[7] = f2bf(f1.w * QSC);
            qf[kc] = a;
        }
    }

    f32x4 oacc[8];
    #pragma unroll
    for (int dt = 0; dt < 8; ++dt) oacc[dt] = (f32x4){0.f, 0.f, 0.f, 0.f};
    float mrun[4]  = {-1e30f, -1e30f, -1e30f, -1e30f};
    float lpart[4] = {0.f, 0.f, 0.f, 0.f};   // per-lane partial row sums

    const short* ktile0 = Kz + (size_t)bh * S_ * Dh;
    const short* vtile0 = Vt + (size_t)bh * S_ * Dh;

    auto STAGE = [&](short* kl, short* vl, int t) {
        const short* kt = ktile0 + (size_t)t * (KVB * Dh);
        const short* vt = vtile0 + (size_t)t * (Dh * KVB);
        #pragma unroll
        for (int i = 0; i < 2; ++i) {
            const int o = (i * 8 + w) * 512;
            gload16(kt + o + lane * 8, kl + o);
            gload16(vt + o + lane * 8, vl + o);
        }
    };

    auto COMPUTE = [&](const short* kl, const short* vl) {
        // ---- S = Q K^T (log2 domain): 16 MFMA ----
        f32x4 sac[4];
        #pragma unroll
        for (int ct = 0; ct < 4; ++ct) sac[ct] = (f32x4){0.f, 0.f, 0.f, 0.f};
        __builtin_amdgcn_s_setprio(1);
        #pragma unroll
        for (int kc = 0; kc < 4; ++kc) {
            #pragma unroll
            for (int ct = 0; ct < 4; ++ct) {
                const short8 b = *(const short8*)
                    &kl[(ct * 16 + lr) * Dh + (((kc * 4 + lg) ^ lr) * 8)];
                sac[ct] = MFMA16(qf[kc], b, sac[ct]);
            }
        }
        __builtin_amdgcn_s_setprio(0);

        // ---- defer-max: lane-local check, full reduce+rescale only if needed
        float mxl[4];
        bool need = false;
        #pragma unroll
        for (int r = 0; r < 4; ++r) {
            mxl[r] = fmaxf(fmaxf(sac[0][r], sac[1][r]),
                           fmaxf(sac[2][r], sac[3][r]));
            need |= (mxl[r] > mrun[r] + 11.0f);
        }
        if (__any(need)) {
            #pragma unroll
            for (int r = 0; r < 4; ++r) {
                float m0 = mxl[r];
                #pragma unroll
                for (int mm = 1; mm < 16; mm <<= 1)
                    m0 = fmaxf(m0, __shfl_xor(m0, mm));
                float mnew = fmaxf(mrun[r], m0);
                float rc = EXP2(mrun[r] - mnew);
                mrun[r] = mnew;
                lpart[r] *= rc;
                #pragma unroll
                for (int dt = 0; dt < 8; ++dt) oacc[dt][r] *= rc;
            }
        }

        // ---- P (bf16, <= 2^11) and PV, interleaved by kv-half ----
        #pragma unroll
        for (int half = 0; half < 2; ++half) {
            #pragma unroll
            for (int r = 0; r < 4; ++r) {
                const int row = lg * 4 + r;
                float psum = 0.f;
                #pragma unroll
                for (int c2 = 0; c2 < 2; ++c2) {
                    const int ct = half * 2 + c2;
                    float p = EXP2(sac[ct][r] - mrun[r]);
                    psum += p;
                    p_lds[w][row][(((ct * 2 + (lr >> 3)) ^ (row & 7)) * 8) + (lr & 7)]
                        = f2bf(p);
                }
                lpart[r] += psum;
            }
            const short8 ap = *(const short8*)
                &p_lds[w][lr][((half * 4 + lg) ^ (lr & 7)) * 8];
            __builtin_amdgcn_s_setprio(1);
            #pragma unroll
            for (int dt = 0; dt < 8; ++dt) {
                const short8 bv = *(const short8*)
                    &vl[(dt * 16 + lr) * KVB + (((half * 4 + lg) ^ (lr & 7)) * 8)];
                oacc[dt] = MFMA16(ap, bv, oacc[dt]);
            }
            __builtin_amdgcn_s_setprio(0);
        }
    };

    // ---- 2-phase pipeline: stage t+1 before compute t, one barrier/tile ----
    STAGE(k0, v0, 0);
    __syncthreads();
    #pragma unroll 1
    for (int t = 0; t < NT; t += 2) {
        STAGE(k1, v1, t + 1);
        COMPUTE(k0, v0);
        __syncthreads();
        if (t + 2 < NT) STAGE(k0, v0, t + 2);
        COMPUTE(k1, v1);
        __syncthreads();
    }

    // ---- epilogue: reduce row sums once, store ----
    float linv[4];
    #pragma unroll
    for (int r = 0; r < 4; ++r) {
        float s = lpart[r];
        #pragma unroll
        for (int mm = 1; mm < 16; mm <<= 1) s += __shfl_xor(s, mm);
        linv[r] = 1.0f / s;
    }
    float* op = Og + base;
    #pragma unroll
    for (int dt = 0; dt < 8; ++dt)
        #pragma unroll
        for (int r = 0; r < 4; ++r)
            op[(size_t)(qrow0 + lg * 4 + r) * Dh + dt * 16 + lr]
                = oacc[dt][r] * linv[r];
}

// ---------------- fallback (round-1 style, used only if ws too small) ------
constexpr int FKVB = 32;
constexpr int FKP  = 136;
constexpr int FVP  = 40;
constexpr int FPP  = 40;

__global__ __launch_bounds__(256, 2)
void mea_fwd_fb(const float* __restrict__ Qg, const float* __restrict__ Kg,
                const float* __restrict__ Vg, float* __restrict__ Og,
                int S, int nqt) {
    __shared__ __align__(16) short k_lds[FKVB][FKP];
    __shared__ __align__(16) short vT_lds[Dh][FVP];
    __shared__ __align__(16) short p_lds[4][16][FPP];

    const int qt = blockIdx.x % nqt;
    const int bh = blockIdx.x / nqt;
    const int tid = threadIdx.x;
    const int w = tid >> 6, lane = tid & 63;
    const int lr = lane & 15, lg = lane >> 4;
    const size_t base = (size_t)bh * S * Dh;
    const int qrow0 = qt * 64 + w * 16;
    const float scale = 0.08838834764831845f;

    short8 qf[4];
    {
        const float* qp = Qg + base + (size_t)(qrow0 + lr) * Dh;
        #pragma unroll
        for (int kc = 0; kc < 4; ++kc) {
            const float4 f0 = *(const float4*)(qp + kc * 32 + lg * 8);
            const float4 f1 = *(const float4*)(qp + kc * 32 + lg * 8 + 4);
            short8 a;
            a[0] = f2bf(f0.x); a[1] = f2bf(f0.y); a[2] = f2bf(f0.z); a[3] = f2bf(f0.w);
            a[4] = f2bf(f1.x); a[5] = f2bf(f1.y); a[6] = f2bf(f1.z); a[7] = f2bf(f1.w);
            qf[kc] = a;
        }
    }
    f32x4 oacc[8];
    #pragma unroll
    for (int dt = 0; dt < 8; ++dt) oacc[dt] = (f32x4){0.f, 0.f, 0.f, 0.f};
    float mrun[4] = {-1e30f, -1e30f, -1e30f, -1e30f};
    float lrun[4] = {0.f, 0.f, 0.f, 0.f};
    const int sr = tid >> 3, sc = (tid & 7) * 16;

    for (int kv0 = 0; kv0 < S; kv0 += FKVB) {
        {
            const float* kp = Kg + base + (size_t)(kv0 + sr) * Dh + sc;
            const float* vp = Vg + base + (size_t)(kv0 + sr) * Dh + sc;
            short8 pk0, pk1;
            float4 f0 = ((const float4*)kp)[0], f1 = ((const float4*)kp)[1];
            float4 f2 = ((const float4*)kp)[2], f3 = ((const float4*)kp)[3];
            pk0[0] = f2bf(f0.x); pk0[1] = f2bf(f0.y); pk0[2] = f2bf(f0.z); pk0[3] = f2bf(f0.w);
            pk0[4] = f2bf(f1.x); pk0[5] = f2bf(f1.y); pk0[6] = f2bf(f1.z); pk0[7] = f2bf(f1.w);
            pk1[0] = f2bf(f2.x); pk1[1] = f2bf(f2.y); pk1[2] = f2bf(f2.z); pk1[3] = f2bf(f2.w);
            pk1[4] = f2bf(f3.x); pk1[5] = f2bf(f3.y); pk1[6] = f2bf(f3.z); pk1[7] = f2bf(f3.w);
            *(short8*)&k_lds[sr][sc] = pk0;
            *(short8*)&k_lds[sr][sc + 8] = pk1;
            #pragma unroll
            for (int i = 0; i < 4; ++i) {
                float4 f = ((const float4*)vp)[i];
                vT_lds[sc + 4 * i + 0][sr] = f2bf(f.x);
                vT_lds[sc + 4 * i + 1][sr] = f2bf(f.y);
                vT_lds[sc + 4 * i + 2][sr] = f2bf(f.z);
                vT_lds[sc + 4 * i + 3][sr] = f2bf(f.w);
            }
        }
        __syncthreads();
        f32x4 s0 = (f32x4){0.f,0.f,0.f,0.f}, s1 = (f32x4){0.f,0.f,0.f,0.f};
        #pragma unroll
        for (int kc = 0; kc < 4; ++kc) {
            short8 b0 = *(const short8*)&k_lds[lr][kc * 32 + lg * 8];
            short8 b1 = *(const short8*)&k_lds[16 + lr][kc * 32 + lg * 8];
            s0 = MFMA16(qf[kc], b0, s0);
            s1 = MFMA16(qf[kc], b1, s1);
        }
        float resc[4];
        #pragma unroll
        for (int r = 0; r < 4; ++r) {
            float mxv = fmaxf(s0[r], s1[r]);
            #pragma unroll
            for (int m = 1; m < 16; m <<= 1) mxv = fmaxf(mxv, __shfl_xor(mxv, m));
            float mnew = fmaxf(mrun[r], mxv * scale);
            float rc = __expf(mrun[r] - mnew);
            mrun[r] = mnew;
            float p0 = __expf(s0[r] * scale - mnew);
            float p1 = __expf(s1[r] * scale - mnew);
            float rs = p0 + p1;
            #pragma unroll
            for (int m = 1; m < 16; m <<= 1) rs += __shfl_xor(rs, m);
            lrun[r] = lrun[r] * rc + rs;
            resc[r] = rc;
            p_lds[w][lg * 4 + r][lr] = f2bf(p0);
            p_lds[w][lg * 4 + r][16 + lr] = f2bf(p1);
        }
        #pragma unroll
        for (int dt = 0; dt < 8; ++dt) {
            f32x4 o = oacc[dt];
            o[0] *= resc[0]; o[1] *= resc[1]; o[2] *= resc[2]; o[3] *= resc[3];
            oacc[dt] = o;
        }
        short8 ap = *(const short8*)&p_lds[w][lr][lg * 8];
        #pragma unroll
        for (int dt = 0; dt < 8; ++dt) {
            short8 bv = *(const short8*)&vT_lds[dt * 16 + lr][lg * 8];
            oacc[dt] = MFMA16(ap, bv, oacc[dt]);
        }
        __syncthreads();
    }
    float inv[4];
    #pragma unroll
    for (int r = 0; r < 4; ++r) inv[r] = 1.0f / lrun[r];
    float* op = Og + base;
    #pragma unroll
    for (int dt = 0; dt < 8; ++dt)
        #pragma unroll
        for (int r = 0; r < 4; ++r)
            op[(size_t)(qrow0 + lg * 4 + r) * Dh + dt * 16 + lr] = oacc[dt][r] * inv[r];
}

extern "C" void kernel_launch(void* const* d_in, const int* in_sizes, int n_in,
                              void* d_out, int out_size, void* d_ws, size_t ws_size,
                              hipStream_t stream) {
    const float* q = (const float*)d_in[0];
    const float* k = (const float*)d_in[1];
    const float* v = (const float*)d_in[2];
    float* o = (float*)d_out;

    const int BH  = in_sizes[0] / (S_ * Dh);     // 32
    const int nqt = S_ / QBLK;                    // 16

    const size_t kz_bytes = (size_t)BH * S_ * Dh * sizeof(short);   // 16.78 MB
    const size_t need = 2 * kz_bytes;

    if (ws_size >= need) {
        short* Kz = (short*)d_ws;
        short* Vt = (short*)((char*)d_ws + kz_bytes);
        hipLaunchKernelGGL(prep_k, dim3(BH * S_ * 16 / 256), dim3(256), 0, stream, k, Kz);
        hipLaunchKernelGGL(prep_v, dim3(BH * (S_ / 64) * 2), dim3(256), 0, stream, v, Vt);
        hipLaunchKernelGGL(mea_fwd3, dim3(BH * nqt), dim3(512), 0, stream, q, Kz, Vt, o, nqt);
    } else {
        hipLaunchKernelGGL(mea_fwd_fb, dim3(BH * (S_ / 64)), dim3(256), 0, stream,
                           q, k, v, o, S_, S_ / 64);
    }
}

// Round 4
// 96.710 us; speedup vs baseline: 3.3368x; 1.1782x over previous
//
#include <hip/hip_runtime.h>
#include <hip/hip_bf16.h>

// MemoryEfficientAttention round 4: swapped-QK 32x32 MFMA structure (m214 recipe)
//  - mfma_f32_32x32x16_bf16: 2x FLOP per LDS byte vs 16x16x32
//  - S^T = mfma(K, Q): softmax lane-local (col=lane&31 = q-row)
//  - P stays in registers: cvt_pk_bf16 pack + shfl_xor(32) exchange (T12)
//  - V pre-transposed in ws -> PV B-frags are plain conflict-free ds_read_b128
//  - 8 waves x 32 q = 256 q/block, grid 256 (1 block/CU), KVB=64 dbuf, 2-phase

typedef short short8 __attribute__((ext_vector_type(8)));
typedef float f32x16 __attribute__((ext_vector_type(16)));

#define MFMA32(a, b, c) __builtin_amdgcn_mfma_f32_32x32x16_bf16((a), (b), (c), 0, 0, 0)

#if __has_builtin(__builtin_amdgcn_exp2f)
#define EXP2(x) __builtin_amdgcn_exp2f(x)
#else
#define EXP2(x) exp2f(x)
#endif

constexpr int Dh  = 128;
constexpr int S_  = 2048;
constexpr int KVB = 64;
constexpr int NT  = S_ / KVB;          // 32 kv tiles
constexpr int WAVES = 8;
constexpr int QBLK  = 256;             // 8 waves x 32 q-rows

__device__ __forceinline__ short f2bf(float f) {
    union { float f; unsigned u; } x; x.f = f;
    unsigned r = x.u + 0x7fffu + ((x.u >> 16) & 1u);   // RNE
    return (short)(r >> 16);
}

// packed RNE f32x2 -> bf16x2 (T12; verified recipe from m214 v22)
__device__ __forceinline__ unsigned pkbf(float lo, float hi) {
    unsigned r;
    asm("v_cvt_pk_bf16_f32 %0, %1, %2" : "=v"(r) : "v"(lo), "v"(hi));
    return r;
}

__device__ __forceinline__ void gload16(const void* g, void* l) {
    __builtin_amdgcn_global_load_lds(
        (const __attribute__((address_space(1))) unsigned int*)g,
        (__attribute__((address_space(3))) unsigned int*)l, 16, 0, 0);
}

// ---------------- pre-pass: K fp32 -> bf16, 16B blocks XOR'd by row&15 -----
__global__ __launch_bounds__(256) void prep_k(const float* __restrict__ K,
                                              short* __restrict__ Kz) {
    int idx = blockIdx.x * 256 + threadIdx.x;     // one 16B out block
    int b   = idx & 15;
    int s   = (idx >> 4) & (S_ - 1);
    int sb  = b ^ (s & 15);
    const float* src = K + (size_t)(idx >> 4) * Dh + sb * 8;
    float4 f0 = ((const float4*)src)[0];
    float4 f1 = ((const float4*)src)[1];
    short8 o;
    o[0] = f2bf(f0.x); o[1] = f2bf(f0.y); o[2] = f2bf(f0.z); o[3] = f2bf(f0.w);
    o[4] = f2bf(f1.x); o[5] = f2bf(f1.y); o[6] = f2bf(f1.z); o[7] = f2bf(f1.w);
    *(short8*)(Kz + (size_t)idx * 8) = o;
}

// ---------------- pre-pass: V fp32 -> bf16 transposed tiles ----------------
// Vt[bh][seg][d][64]: row d holds V[seg*64 .. +63][d]; 16B block j stores
// s-block (j ^ (d&7)).
__global__ __launch_bounds__(256) void prep_v(const float* __restrict__ V,
                                              short* __restrict__ Vt) {
    __shared__ short tr[64][72];
    int bid = blockIdx.x;
    int dg = bid & 1, seg = (bid >> 1) & 31, bh = bid >> 6;
    int t = threadIdx.x;
    int s = t >> 2, d0 = (t & 3) * 16;
    const float* src = V + (size_t)(bh * S_ + seg * 64 + s) * Dh + dg * 64 + d0;
    #pragma unroll
    for (int i = 0; i < 16; i += 4) {
        float4 f = *(const float4*)(src + i);
        tr[d0 + i + 0][s] = f2bf(f.x); tr[d0 + i + 1][s] = f2bf(f.y);
        tr[d0 + i + 2][s] = f2bf(f.z); tr[d0 + i + 3][s] = f2bf(f.w);
    }
    __syncthreads();
    int d = t >> 2, j0 = (t & 3) * 2;
    size_t ob = ((size_t)(bh * 32 + seg) * 128 + dg * 64 + d) * 64;
    #pragma unroll
    for (int jj = 0; jj < 2; ++jj) {
        int j = j0 + jj;
        int sj = (j ^ (d & 7)) * 8;
        short8 val = *(const short8*)&tr[d][sj];
        *(short8*)(Vt + ob + j * 8) = val;
    }
}

// ---------------- main flash kernel (8-wave, 32x32, swapped QK) ------------
__global__ __launch_bounds__(512, 2)
void mea_fwd4(const float* __restrict__ Qg, const short* __restrict__ Kz,
              const short* __restrict__ Vt, float* __restrict__ Og, int nqt) {
    __shared__ __align__(16) short k0[KVB * Dh], k1[KVB * Dh];
    __shared__ __align__(16) short v0[Dh * KVB], v1[Dh * KVB];
    __shared__ float bc_lds[WAVES][32];    // rare-path row broadcast

    // bijective XCD swizzle (grid % 8 == 0): keeps one bh's blocks on one XCD
    const int bid = blockIdx.x;
    const int cpx = (int)gridDim.x >> 3;
    const int swz = (bid & 7) * cpx + (bid >> 3);
    const int qt  = swz % nqt;
    const int bh  = swz / nqt;

    const int tid  = threadIdx.x;
    const int w    = tid >> 6;
    const int lane = tid & 63;
    const int l31  = lane & 31;
    const int hi   = lane >> 5;

    const size_t base = (size_t)bh * S_ * Dh;
    const int    qrow = qt * QBLK + w * 32 + l31;   // this lane's softmax row
    const float  QSC  = 0.08838834764831845f * 1.4426950408889634f; // scale*log2e

    // ---- Q B-frags: lane holds Q[qrow][kc*16 + hi*8 .. +7], pre-scaled ----
    short8 qf[8];
    {
        const float* qp = Qg + base + (size_t)qrow * Dh;
        #pragma unroll
        for (int kc = 0; kc < 8; ++kc) {
            const float4 f0 = *(const float4*)(qp + kc * 16 + hi * 8);
            const float4 f1 = *(const float4*)(qp + kc * 16 + hi * 8 + 4);
            short8 a;
            a[0] = f2bf(f0.x * QSC); a[1] = f2bf(f0.y * QSC);
            a[2] = f2bf(f0.z * QSC); a[3] = f2bf(f0.w * QSC);
            a[4] = f2bf(f1.x * QSC); a[5] = f2bf(f1.y * QSC);
            a[6] = f2bf(f1.z * QSC); a[7] = f2bf(f1.w * QSC);
            qf[kc] = a;
        }
    }

    f32x16 oacc[4];
    #pragma unroll
    for (int dt = 0; dt < 4; ++dt)
        #pragma unroll
        for (int r = 0; r < 16; ++r) oacc[dt][r] = 0.f;
    float mrun = -1e30f, lpart = 0.f;

    const short* kt0 = Kz + base;           // [64 kv][128 d] tiles, contiguous
    const short* vt0 = Vt + base;           // [128 d][64 kv] tiles, contiguous

    auto STAGE = [&](short* kl, short* vl, int t) {
        const short* ks = kt0 + (size_t)t * (KVB * Dh);
        const short* vs = vt0 + (size_t)t * (Dh * KVB);
        #pragma unroll
        for (int i = 0; i < 2; ++i) {
            const int ou = (i * 8 + w) * 512;        // wave-uniform LDS offset
            gload16(ks + ou + lane * 8, kl + ou);
            gload16(vs + ou + lane * 8, vl + ou);
        }
    };

    auto COMPUTE = [&](const short* kl, const short* vl) {
        // ---- S^T = K Q : two kv-half 32x32 tiles, D=128 via 8 MFMA each ----
        f32x16 sa, sb;
        #pragma unroll
        for (int r = 0; r < 16; ++r) { sa[r] = 0.f; sb[r] = 0.f; }
        __builtin_amdgcn_s_setprio(1);
        #pragma unroll
        for (int kc = 0; kc < 8; ++kc) {
            const int go = (((kc * 2 + hi) ^ (l31 & 15)) * 8);
            const short8 a0 = *(const short8*)&kl[l31 * Dh + go];
            const short8 a1 = *(const short8*)&kl[(32 + l31) * Dh + go];
            sa = MFMA32(a0, qf[kc], sa);
            sb = MFMA32(a1, qf[kc], sb);
        }
        __builtin_amdgcn_s_setprio(0);

        // ---- lane-local softmax (q = l31), defer-max THR=8 ----
        float mxl = sa[0];
        #pragma unroll
        for (int r = 1; r < 16; ++r) mxl = fmaxf(mxl, sa[r]);
        #pragma unroll
        for (int r = 0; r < 16; ++r) mxl = fmaxf(mxl, sb[r]);
        if (__any(mxl > mrun + 8.0f)) {
            float mo   = fmaxf(mxl, __shfl_xor(mxl, 32));
            float mnew = fmaxf(mrun, mo);
            float rc   = EXP2(mrun - mnew);
            mrun = mnew;
            lpart *= rc;
            if (!hi) bc_lds[w][l31] = rc;
            // rescale O: rows (reg&3)+8*(reg>>2)+4*hi -> quads at m*8+4hi
            #pragma unroll
            for (int m = 0; m < 4; ++m) {
                const float4 rcv = *(const float4*)&bc_lds[w][m * 8 + 4 * hi];
                #pragma unroll
                for (int t2 = 0; t2 < 4; ++t2) {
                    const float f = (&rcv.x)[t2];
                    #pragma unroll
                    for (int dt = 0; dt < 4; ++dt) oacc[dt][m * 4 + t2] *= f;
                }
            }
        }

        // ---- P = exp2(S - m), in-register ----
        f32x16 pa, pb;
        float s0 = 0.f, s1 = 0.f;
        #pragma unroll
        for (int r = 0; r < 16; ++r) { pa[r] = EXP2(sa[r] - mrun); s0 += pa[r]; }
        #pragma unroll
        for (int r = 0; r < 16; ++r) { pb[r] = EXP2(sb[r] - mrun); s1 += pb[r]; }
        lpart += s0 + s1;

        // ---- pack to PV A-frags: 16 cvt_pk + 8 shfl_xor(32) (T12) ----
        short8 pf[4];
        #pragma unroll
        for (int ks = 0; ks < 4; ++ks) {
            const int qA = (ks & 1) * 2, qB = qA + 1;
            float eA0, eA1, eA2, eA3, eB0, eB1, eB2, eB3;
            if (ks < 2) {
                eA0 = pa[qA*4+0]; eA1 = pa[qA*4+1]; eA2 = pa[qA*4+2]; eA3 = pa[qA*4+3];
                eB0 = pa[qB*4+0]; eB1 = pa[qB*4+1]; eB2 = pa[qB*4+2]; eB3 = pa[qB*4+3];
            } else {
                eA0 = pb[qA*4+0]; eA1 = pb[qA*4+1]; eA2 = pb[qA*4+2]; eA3 = pb[qA*4+3];
                eB0 = pb[qB*4+0]; eB1 = pb[qB*4+1]; eB2 = pb[qB*4+2]; eB3 = pb[qB*4+3];
            }
            const unsigned uA0 = pkbf(eA0, eA1), uA1 = pkbf(eA2, eA3);
            const unsigned uB0 = pkbf(eB0, eB1), uB1 = pkbf(eB2, eB3);
            const unsigned y0 = hi ? uA0 : uB0;
            const unsigned y1 = hi ? uA1 : uB1;
            const unsigned r0 = (unsigned)__shfl_xor((int)y0, 32);
            const unsigned r1 = (unsigned)__shfl_xor((int)y1, 32);
            unsigned wd[4];
            wd[0] = hi ? r0 : uA0;  wd[1] = hi ? r1 : uA1;
            wd[2] = hi ? uB0 : r0;  wd[3] = hi ? uB1 : r1;
            pf[ks] = *(const short8*)wd;
        }

        // ---- O += P V : 4 d-tiles x 4 kv-slices = 16 MFMA ----
        __builtin_amdgcn_s_setprio(1);
        #pragma unroll
        for (int dt = 0; dt < 4; ++dt) {
            #pragma unroll
            for (int ks = 0; ks < 4; ++ks) {
                const short8 bv = *(const short8*)
                    &vl[(dt * 32 + l31) * KVB + (((ks * 2 + hi) ^ (l31 & 7)) * 8)];
                oacc[dt] = MFMA32(pf[ks], bv, oacc[dt]);
            }
        }
        __builtin_amdgcn_s_setprio(0);
    };

    // ---- 2-phase pipeline: stage t+1 before compute t, one barrier/tile ----
    STAGE(k0, v0, 0);
    __syncthreads();
    #pragma unroll 1
    for (int t = 0; t < NT; t += 2) {
        STAGE(k1, v1, t + 1);
        COMPUTE(k0, v0);
        __syncthreads();
        if (t + 2 < NT) STAGE(k0, v0, t + 2);
        COMPUTE(k1, v1);
        __syncthreads();
    }

    // ---- epilogue: total row sum via lane^32, broadcast 1/l, store ----
    {
        const float tot = lpart + __shfl_xor(lpart, 32);
        if (!hi) bc_lds[w][l31] = 1.0f / tot;
    }
    float* op = Og + base;
    #pragma unroll
    for (int m = 0; m < 4; ++m) {
        const float4 li = *(const float4*)&bc_lds[w][m * 8 + 4 * hi];
        #pragma unroll
        for (int t2 = 0; t2 < 4; ++t2) {
            const int row  = m * 8 + 4 * hi + t2;
            const float lf = (&li.x)[t2];
            #pragma unroll
            for (int dt = 0; dt < 4; ++dt)
                op[(size_t)(qt * QBLK + w * 32 + row) * Dh + dt * 32 + l31]
                    = oacc[dt][m * 4 + t2] * lf;
        }
    }
}

// ---------------- fallback (no-ws path) ------------------------------------
typedef float f32x4 __attribute__((ext_vector_type(4)));
#define MFMA16(a, b, c) __builtin_amdgcn_mfma_f32_16x16x32_bf16((a), (b), (c), 0, 0, 0)
constexpr int FKVB = 32;
constexpr int FKP  = 136;
constexpr int FVP  = 40;
constexpr int FPP  = 40;

__global__ __launch_bounds__(256, 2)
void mea_fwd_fb(const float* __restrict__ Qg, const float* __restrict__ Kg,
                const float* __restrict__ Vg, float* __restrict__ Og,
                int S, int nqt) {
    __shared__ __align__(16) short k_lds[FKVB][FKP];
    __shared__ __align__(16) short vT_lds[Dh][FVP];
    __shared__ __align__(16) short p_lds[4][16][FPP];

    const int qt = blockIdx.x % nqt;
    const int bh = blockIdx.x / nqt;
    const int tid = threadIdx.x;
    const int w = tid >> 6, lane = tid & 63;
    const int lr = lane & 15, lg = lane >> 4;
    const size_t base = (size_t)bh * S * Dh;
    const int qrow0 = qt * 64 + w * 16;
    const float scale = 0.08838834764831845f;

    short8 qf[4];
    {
        const float* qp = Qg + base + (size_t)(qrow0 + lr) * Dh;
        #pragma unroll
        for (int kc = 0; kc < 4; ++kc) {
            const float4 f0 = *(const float4*)(qp + kc * 32 + lg * 8);
            const float4 f1 = *(const float4*)(qp + kc * 32 + lg * 8 + 4);
            short8 a;
            a[0] = f2bf(f0.x); a[1] = f2bf(f0.y); a[2] = f2bf(f0.z); a[3] = f2bf(f0.w);
            a[4] = f2bf(f1.x); a[5] = f2bf(f1.y); a[6] = f2bf(f1.z); a[7] = f2bf(f1.w);
            qf[kc] = a;
        }
    }
    f32x4 oacc[8];
    #pragma unroll
    for (int dt = 0; dt < 8; ++dt) oacc[dt] = (f32x4){0.f, 0.f, 0.f, 0.f};
    float mrun[4] = {-1e30f, -1e30f, -1e30f, -1e30f};
    float lrun[4] = {0.f, 0.f, 0.f, 0.f};
    const int sr = tid >> 3, sc = (tid & 7) * 16;

    for (int kv0 = 0; kv0 < S; kv0 += FKVB) {
        {
            const float* kp = Kg + base + (size_t)(kv0 + sr) * Dh + sc;
            const float* vp = Vg + base + (size_t)(kv0 + sr) * Dh + sc;
            short8 pk0, pk1;
            float4 f0 = ((const float4*)kp)[0], f1 = ((const float4*)kp)[1];
            float4 f2 = ((const float4*)kp)[2], f3 = ((const float4*)kp)[3];
            pk0[0] = f2bf(f0.x); pk0[1] = f2bf(f0.y); pk0[2] = f2bf(f0.z); pk0[3] = f2bf(f0.w);
            pk0[4] = f2bf(f1.x); pk0[5] = f2bf(f1.y); pk0[6] = f2bf(f1.z); pk0[7] = f2bf(f1.w);
            pk1[0] = f2bf(f2.x); pk1[1] = f2bf(f2.y); pk1[2] = f2bf(f2.z); pk1[3] = f2bf(f2.w);
            pk1[4] = f2bf(f3.x); pk1[5] = f2bf(f3.y); pk1[6] = f2bf(f3.z); pk1[7] = f2bf(f3.w);
            *(short8*)&k_lds[sr][sc] = pk0;
            *(short8*)&k_lds[sr][sc + 8] = pk1;
            #pragma unroll
            for (int i = 0; i < 4; ++i) {
                float4 f = ((const float4*)vp)[i];
                vT_lds[sc + 4 * i + 0][sr] = f2bf(f.x);
                vT_lds[sc + 4 * i + 1][sr] = f2bf(f.y);
                vT_lds[sc + 4 * i + 2][sr] = f2bf(f.z);
                vT_lds[sc + 4 * i + 3][sr] = f2bf(f.w);
            }
        }
        __syncthreads();
        f32x4 s0 = (f32x4){0.f,0.f,0.f,0.f}, s1 = (f32x4){0.f,0.f,0.f,0.f};
        #pragma unroll
        for (int kc = 0; kc < 4; ++kc) {
            short8 b0 = *(const short8*)&k_lds[lr][kc * 32 + lg * 8];
            short8 b1 = *(const short8*)&k_lds[16 + lr][kc * 32 + lg * 8];
            s0 = MFMA16(qf[kc], b0, s0);
            s1 = MFMA16(qf[kc], b1, s1);
        }
        float resc[4];
        #pragma unroll
        for (int r = 0; r < 4; ++r) {
            float mxv = fmaxf(s0[r], s1[r]);
            #pragma unroll
            for (int m = 1; m < 16; m <<= 1) mxv = fmaxf(mxv, __shfl_xor(mxv, m));
            float mnew = fmaxf(mrun[r], mxv * scale);
            float rc = __expf(mrun[r] - mnew);
            mrun[r] = mnew;
            float p0 = __expf(s0[r] * scale - mnew);
            float p1 = __expf(s1[r] * scale - mnew);
            float rs = p0 + p1;
            #pragma unroll
            for (int m = 1; m < 16; m <<= 1) rs += __shfl_xor(rs, m);
            lrun[r] = lrun[r] * rc + rs;
            resc[r] = rc;
            p_lds[w][lg * 4 + r][lr] = f2bf(p0);
            p_lds[w][lg * 4 + r][16 + lr] = f2bf(p1);
        }
        #pragma unroll
        for (int dt = 0; dt < 8; ++dt) {
            f32x4 o = oacc[dt];
            o[0] *= resc[0]; o[1] *= resc[1]; o[2] *= resc[2]; o[3] *= resc[3];
            oacc[dt] = o;
        }
        short8 ap = *(const short8*)&p_lds[w][lr][lg * 8];
        #pragma unroll
        for (int dt = 0; dt < 8; ++dt) {
            short8 bv = *(const short8*)&vT_lds[dt * 16 + lr][lg * 8];
            oacc[dt] = MFMA16(ap, bv, oacc[dt]);
        }
        __syncthreads();
    }
    float inv[4];
    #pragma unroll
    for (int r = 0; r < 4; ++r) inv[r] = 1.0f / lrun[r];
    float* op = Og + base;
    #pragma unroll
    for (int dt = 0; dt < 8; ++dt)
        #pragma unroll
        for (int r = 0; r < 4; ++r)
            op[(size_t)(qrow0 + lg * 4 + r) * Dh + dt * 16 + lr] = oacc[dt][r] * inv[r];
}

extern "C" void kernel_launch(void* const* d_in, const int* in_sizes, int n_in,
                              void* d_out, int out_size, void* d_ws, size_t ws_size,
                              hipStream_t stream) {
    const float* q = (const float*)d_in[0];
    const float* k = (const float*)d_in[1];
    const float* v = (const float*)d_in[2];
    float* o = (float*)d_out;

    const int BH  = in_sizes[0] / (S_ * Dh);     // 32
    const int nqt = S_ / QBLK;                    // 8

    const size_t kz_bytes = (size_t)BH * S_ * Dh * sizeof(short);   // 16.78 MB
    const size_t need = 2 * kz_bytes;

    if (ws_size >= need) {
        short* Kz = (short*)d_ws;
        short* Vt = (short*)((char*)d_ws + kz_bytes);
        hipLaunchKernelGGL(prep_k, dim3(BH * S_ * 16 / 256), dim3(256), 0, stream, k, Kz);
        hipLaunchKernelGGL(prep_v, dim3(BH * (S_ / 64) * 2), dim3(256), 0, stream, v, Vt);
        hipLaunchKernelGGL(mea_fwd4, dim3(BH * nqt), dim3(512), 0, stream, q, Kz, Vt, o, nqt);
    } else {
        hipLaunchKernelGGL(mea_fwd_fb, dim3(BH * (S_ / 64)), dim3(256), 0, stream,
                           q, k, v, o, S_, S_ / 64);
    }
}